// Round 2
// baseline (146.575 us; speedup 1.0000x reference)
//
#include <hip/hip_runtime.h>
#include <math.h>

#define NTOK 100
#define EDIM 5
#define NH   4
#define NL   3
#define DD   64
#define BLK  512

#if __has_builtin(__builtin_amdgcn_exp2f)
#define EXP2(x) __builtin_amdgcn_exp2f(x)
#else
#define EXP2(x) exp2f(x)
#endif
#if __has_builtin(__builtin_amdgcn_rcpf)
#define RCPF(x) __builtin_amdgcn_rcpf(x)
#else
#define RCPF(x) (1.f/(x))
#endif
// wave-uniform register broadcast: v_readlane_b32 (lane index in SGPR)
#define RL(v, l) __int_as_float(__builtin_amdgcn_readlane(__float_as_int(v), (l)))

// ---------------------------------------------------------------------------
// Kernel 1: fold per-head projections into 5x5 matrices.
//   M[l][h] = (1/8)*log2(e) * Wq^T Wk    (softmax uses native exp2)
//   P[l][h] = Wv^T Wo_h^T
// ws layout: float [2][NL][NH][EDIM][8]
// ---------------------------------------------------------------------------
__global__ void precompute_mp(const float* __restrict__ Wq,
                              const float* __restrict__ Wk,
                              const float* __restrict__ Wv,
                              const float* __restrict__ Wo,
                              float* __restrict__ mp) {
  const int blk = blockIdx.x;            // 24 = which(2) * l(3) * h(4)
  const int which = blk / 12;
  const int rem = blk % 12;
  const int l = rem / 4, h = rem % 4;
  const int t = threadIdx.x;             // 64 threads

  __shared__ float A[320];               // [d*5+e]
  __shared__ float Bsh[320];             // which0: [d*5+f] ; which1: [f*64+d]

  const float* wa = (which ? Wv : Wq) + (l*NH + h)*DD*EDIM;
  for (int r = t; r < 320; r += 64) A[r] = wa[r];
  if (which == 0) {
    const float* wk = Wk + (l*NH + h)*DD*EDIM;
    for (int r = t; r < 320; r += 64) Bsh[r] = wk[r];
  } else {
    for (int r = t; r < 320; r += 64) {
      int f = r >> 6, d = r & 63;
      Bsh[r] = Wo[(l*EDIM + f)*(NH*DD) + h*DD + d];
    }
  }
  __syncthreads();
  if (t < 25) {
    int e = t / 5, f = t % 5;
    float acc = 0.f;
    if (which == 0) {
      #pragma unroll 8
      for (int d = 0; d < DD; ++d) acc += A[d*5+e] * Bsh[d*5+f];
      acc *= 0.125f * 1.44269504088896340736f;   // fold log2(e) for exp2
    } else {
      #pragma unroll 8
      for (int d = 0; d < DD; ++d) acc += A[d*5+e] * Bsh[f*64+d];
    }
    mp[which*960 + ((l*NH + h)*EDIM + e)*8 + f] = acc;
  }
}

// ---------------------------------------------------------------------------
// Kernel 2: one workgroup (512 thr = 8 waves) per batch element.
//   wave = (head h, j-half g).  Token state lives in REGISTERS, distributed
//   across lanes: lane i holds token i (slot A) and token i+64 (slot B).
//   j-loop fetches o[j] via v_readlane (wave-uniform j) -> zero LDS in the
//   hot loop; broadcast amortized over all 64 rows in the wave.
//   Cross-wave: P-applied partials {wp[5], ls} per (h,g,row) via LDS,
//   2 barriers/layer.  Token update (merge partials, LN/FFN/LN) is computed
//   redundantly by every wave on its own lanes -> all register copies stay
//   bit-identical (deterministic FP), no thin phases.
//   Rep row (index nm): a=0 so exp2(0)=1 gives uniform weights; correction
//   w += (100-nm)*o_rep applied in g==0 only; inv = 1/100.
// ---------------------------------------------------------------------------
__global__ __launch_bounds__(BLK, 8) void encoder_kernel(
    const float* __restrict__ x,
    const float* __restrict__ mp,
    const float* __restrict__ Wf,
    const float* __restrict__ bfv,
    const float* __restrict__ g1,
    const float* __restrict__ b1,
    const float* __restrict__ g2,
    const float* __restrict__ b2,
    float* __restrict__ out)
{
  const int b = blockIdx.x, t = threadIdx.x;
  const int wv = t >> 6, ln = t & 63;
  const int h = wv >> 1, g = wv & 1;

  __shared__ float4 s_MP4[480];            // 7680 B : M then P
  __shared__ float4 s_w4[NH][2][104];      // 13312 B: wp[0..3] per (h,g,row)
  __shared__ float2 s_w2[NH][2][104];      // 6656 B : {wp[4], ls}
  __shared__ float4 s_i4[104];             // 1664 B : staging / final state
  __shared__ float  s_i1[104];             // 416 B
  __shared__ int    s_cidx[NTOK];          // 400 B
  __shared__ unsigned long long s_bal[2];

  const float* mpf = (const float*)s_MP4;
  for (int r = t; r < 480; r += BLK) s_MP4[r] = ((const float4*)mp)[r];
  for (int r = t; r < 104; r += BLK) { s_i4[r] = make_float4(0.f,0.f,0.f,0.f); s_i1[r] = 0.f; }

  // ---- setup: mask + ballot compaction into LDS staging ----
  float k0=0.f, k1=0.f, k2=0.f, msk=0.f;
  if (t < NTOK) {
    k0 = x[b*300 + 3*t];
    k1 = x[b*300 + 3*t + 1];
    k2 = x[b*300 + 3*t + 2];
    msk = (k2 > 0.f) ? 1.f : 0.f;
  }
  unsigned long long bal = __ballot(t < NTOK && msk != 0.f);
  if (t == 0)  s_bal[0] = bal;
  if (t == 64) s_bal[1] = bal;
  __syncthreads();
  const unsigned long long bw0 = s_bal[0], bw1 = s_bal[1];
  const int nm = __popcll(bw0) + __popcll(bw1);     // # unmasked tokens
  if (t < NTOK) {
    int lane = t & 63;
    unsigned long long lm = (lane == 0) ? 0ull : ((1ull << lane) - 1ull);
    int pre = (t < 64) ? __popcll(bw0 & lm) : (__popcll(bw0) + __popcll(bw1 & lm));
    if (msk != 0.f) {
      s_i4[pre] = make_float4(k0, k1, k2, sinf((float)t));
      s_i1[pre] = cosf((float)t);
      s_cidx[t] = pre;
    } else {
      s_cidx[t] = nm;
    }
  }
  __syncthreads();

  const int rows = nm + 1;                  // includes rep token at index nm
  const bool twoRows = (rows > 64);

  // ---- load register-resident token state (identical in every wave) ----
  float oA0,oA1,oA2,oA3,oA4, oB0,oB1,oB2,oB3,oB4;
  { float4 v = s_i4[ln]; oA0=v.x; oA1=v.y; oA2=v.z; oA3=v.w; oA4=s_i1[ln]; }
  if (ln < 40) { float4 v = s_i4[ln+64]; oB0=v.x; oB1=v.y; oB2=v.z; oB3=v.w; oB4=s_i1[ln+64]; }
  else { oB0=0.f; oB1=0.f; oB2=0.f; oB3=0.f; oB4=0.f; }

  const int jmid = nm >> 1;
  const int jlo  = g ? jmid : 0;
  const int jhi  = g ? nm : jmid;
  const int jhiA = (jhi < 64) ? jhi : 64;   // slot-A portion of [jlo,jhi)
  const int jloB = (jlo > 64) ? jlo : 64;   // slot-B portion
  const float wext = (float)(NTOK - nm);

  for (int l = 0; l < NL; ++l) {
    const float* Mh = mpf + ((l*NH + h)*EDIM)*8;
    const float* Ph = mpf + 960 + ((l*NH + h)*EDIM)*8;

    // ---- attention for one register-held row ----
    auto attn_row = [&](float o0,float o1,float o2,float o3,float o4,int row) {
      float oc[5] = {o0,o1,o2,o3,o4};
      float a0=0.f,a1=0.f,a2=0.f,a3=0.f,a4=0.f;
      #pragma unroll
      for (int e = 0; e < 5; ++e) {
        float4 mr = *(const float4*)(Mh + e*8); float m4 = Mh[e*8+4];
        a0 += oc[e]*mr.x; a1 += oc[e]*mr.y; a2 += oc[e]*mr.z;
        a3 += oc[e]*mr.w; a4 += oc[e]*m4;
      }
      const bool rep = (row == nm);
      if (rep) { a0=0.f; a1=0.f; a2=0.f; a3=0.f; a4=0.f; }   // exp2(0)=1
      float ls=0.f, w0=0.f, w1=0.f, w2=0.f, w3=0.f, w4=0.f;
      #pragma unroll 4
      for (int j = jlo; j < jhiA; ++j) {      // keys in slot A (j<64)
        float ox = RL(oA0,j), oy = RL(oA1,j), oz = RL(oA2,j),
              ow = RL(oA3,j), oe = RL(oA4,j);
        float s = a0*ox + a1*oy + a2*oz + a3*ow + a4*oe;
        float p = EXP2(s);
        ls += p;
        w0 += p*ox; w1 += p*oy; w2 += p*oz; w3 += p*ow; w4 += p*oe;
      }
      #pragma unroll 4
      for (int j = jloB; j < jhi; ++j) {      // keys in slot B (j>=64)
        int jl = j - 64;
        float ox = RL(oB0,jl), oy = RL(oB1,jl), oz = RL(oB2,jl),
              ow = RL(oB3,jl), oe = RL(oB4,jl);
        float s = a0*ox + a1*oy + a2*oz + a3*ow + a4*oe;
        float p = EXP2(s);
        ls += p;
        w0 += p*ox; w1 += p*oy; w2 += p*oz; w3 += p*ow; w4 += p*oe;
      }
      if (rep && g == 0) {   // masked keys all carry the rep state
        w0 += wext*o0; w1 += wext*o1; w2 += wext*o2; w3 += wext*o3; w4 += wext*o4;
      }
      float wc[5] = {w0,w1,w2,w3,w4};
      float c0=0.f,c1=0.f,c2=0.f,c3=0.f,c4=0.f;   // wp = w @ P (pre-normalize)
      #pragma unroll
      for (int e = 0; e < 5; ++e) {
        float4 pr = *(const float4*)(Ph + e*8); float p4 = Ph[e*8+4];
        c0 += wc[e]*pr.x; c1 += wc[e]*pr.y; c2 += wc[e]*pr.z;
        c3 += wc[e]*pr.w; c4 += wc[e]*p4;
      }
      if (row < rows) {
        s_w4[h][g][row] = make_float4(c0,c1,c2,c3);
        s_w2[h][g][row] = make_float2(c4, ls);
      }
    };

    attn_row(oA0,oA1,oA2,oA3,oA4, ln);
    if (twoRows) attn_row(oB0,oB1,oB2,oB3,oB4, ln+64);
    __syncthreads();

    // ---- token update: redundant in every wave (regs stay coherent) ----
    auto upd = [&](float& p0,float& p1,float& p2,float& p3,float& p4,int row) {
      if (row >= rows) return;
      const bool rep = (row == nm);
      float y0=p0, y1=p1, y2=p2, y3=p3, y4=p4;
      #pragma unroll
      for (int hh = 0; hh < NH; ++hh) {
        float4 wA = s_w4[hh][0][row], wB = s_w4[hh][1][row];
        float2 lA = s_w2[hh][0][row], lB = s_w2[hh][1][row];
        float ls  = lA.y + lB.y;
        float inv = rep ? 0.01f : RCPF(ls);
        y0 += (wA.x + wB.x)*inv; y1 += (wA.y + wB.y)*inv;
        y2 += (wA.z + wB.z)*inv; y3 += (wA.w + wB.w)*inv;
        y4 += (lA.x + lB.x)*inv;
      }
      float yv[5] = {y0,y1,y2,y3,y4};
      float mu = 0.2f*(y0+y1+y2+y3+y4);
      float var = 0.f;
      #pragma unroll
      for (int e = 0; e < 5; ++e) { float d = yv[e]-mu; var += d*d; }
      var *= 0.2f;
      float iv = 1.f / sqrtf(var + 1e-5f);
      float l1[5];
      #pragma unroll
      for (int e = 0; e < 5; ++e) l1[e] = (yv[e]-mu)*iv*g1[l*5+e] + b1[l*5+e];
      float r2[5];
      #pragma unroll
      for (int e = 0; e < 5; ++e) {
        float acc = bfv[l*5+e];
        #pragma unroll
        for (int f = 0; f < 5; ++f) acc += l1[f]*Wf[(l*5+e)*5+f];
        acc = acc > 0.f ? acc : 0.f;
        r2[e] = acc + l1[e];
      }
      float mu2 = 0.2f*(r2[0]+r2[1]+r2[2]+r2[3]+r2[4]);
      float var2 = 0.f;
      #pragma unroll
      for (int e = 0; e < 5; ++e) { float d = r2[e]-mu2; var2 += d*d; }
      var2 *= 0.2f;
      float iv2 = 1.f / sqrtf(var2 + 1e-5f);
      p0 = (r2[0]-mu2)*iv2*g2[l*5+0] + b2[l*5+0];
      p1 = (r2[1]-mu2)*iv2*g2[l*5+1] + b2[l*5+1];
      p2 = (r2[2]-mu2)*iv2*g2[l*5+2] + b2[l*5+2];
      p3 = (r2[3]-mu2)*iv2*g2[l*5+3] + b2[l*5+3];
      p4 = (r2[4]-mu2)*iv2*g2[l*5+4] + b2[l*5+4];
    };
    upd(oA0,oA1,oA2,oA3,oA4, ln);
    if (twoRows) upd(oB0,oB1,oB2,oB3,oB4, ln+64);
    __syncthreads();   // protect s_w4/s_w2 reuse next layer
  }

  // ---- writeback: wave 0's registers -> LDS, then expand to [N,E] ----
  if (wv == 0) {
    if (ln < rows) { s_i4[ln] = make_float4(oA0,oA1,oA2,oA3); s_i1[ln] = oA4; }
    if (twoRows && (ln + 64 < rows)) {
      s_i4[ln+64] = make_float4(oB0,oB1,oB2,oB3); s_i1[ln+64] = oB4;
    }
  }
  __syncthreads();
  for (int r = t; r < NTOK*EDIM; r += BLK) {
    int i = r / EDIM;
    int e = r - i*EDIM;
    int c = s_cidx[i];
    float v = (e < 4) ? ((const float*)&s_i4[c])[e] : s_i1[c];
    out[b*(NTOK*EDIM) + r] = v;
  }
}

extern "C" void kernel_launch(void* const* d_in, const int* in_sizes, int n_in,
                              void* d_out, int out_size, void* d_ws, size_t ws_size,
                              hipStream_t stream) {
  const float* x  = (const float*)d_in[0];
  const float* Wq = (const float*)d_in[1];
  const float* Wk = (const float*)d_in[2];
  const float* Wv = (const float*)d_in[3];
  const float* Wo = (const float*)d_in[4];
  const float* Wf = (const float*)d_in[5];
  const float* bf = (const float*)d_in[6];
  const float* g1 = (const float*)d_in[7];
  const float* b1 = (const float*)d_in[8];
  const float* g2 = (const float*)d_in[9];
  const float* b2 = (const float*)d_in[10];
  float* outp = (float*)d_out;
  float* mp   = (float*)d_ws;   // 1920 floats

  precompute_mp<<<24, 64, 0, stream>>>(Wq, Wk, Wv, Wo, mp);
  encoder_kernel<<<1024, BLK, 0, stream>>>(x, mp, Wf, bf, g1, b1, g2, b2, outp);
}

// Round 3
// 129.960 us; speedup vs baseline: 1.1278x; 1.1278x over previous
//
#include <hip/hip_runtime.h>
#include <math.h>

#define NTOK 100
#define EDIM 5
#define NH   4
#define NL   3
#define DD   64
#define BLK  256

#if __has_builtin(__builtin_amdgcn_exp2f)
#define EXP2(x) __builtin_amdgcn_exp2f(x)
#else
#define EXP2(x) exp2f(x)
#endif
#if __has_builtin(__builtin_amdgcn_rcpf)
#define RCPF(x) __builtin_amdgcn_rcpf(x)
#else
#define RCPF(x) (1.f/(x))
#endif
// wave-uniform register broadcast: v_readlane_b32 (lane index in SGPR)
#define RL(v, l) __int_as_float(__builtin_amdgcn_readlane(__float_as_int(v), (l)))

// ---------------------------------------------------------------------------
// Kernel 1: fold per-head projections into 5x5 matrices.
//   M[l][h] = (1/8)*log2(e) * Wq^T Wk    (softmax uses native exp2)
//   P[l][h] = Wv^T Wo_h^T
// ws layout: float [2][NL][NH][EDIM][8]
// ---------------------------------------------------------------------------
__global__ void precompute_mp(const float* __restrict__ Wq,
                              const float* __restrict__ Wk,
                              const float* __restrict__ Wv,
                              const float* __restrict__ Wo,
                              float* __restrict__ mp) {
  const int blk = blockIdx.x;            // 24 = which(2) * l(3) * h(4)
  const int which = blk / 12;
  const int rem = blk % 12;
  const int l = rem / 4, h = rem % 4;
  const int t = threadIdx.x;             // 64 threads

  __shared__ float A[320];               // [d*5+e]
  __shared__ float Bsh[320];             // which0: [d*5+f] ; which1: [f*64+d]

  const float* wa = (which ? Wv : Wq) + (l*NH + h)*DD*EDIM;
  for (int r = t; r < 320; r += 64) A[r] = wa[r];
  if (which == 0) {
    const float* wk = Wk + (l*NH + h)*DD*EDIM;
    for (int r = t; r < 320; r += 64) Bsh[r] = wk[r];
  } else {
    for (int r = t; r < 320; r += 64) {
      int f = r >> 6, d = r & 63;
      Bsh[r] = Wo[(l*EDIM + f)*(NH*DD) + h*DD + d];
    }
  }
  __syncthreads();
  if (t < 25) {
    int e = t / 5, f = t % 5;
    float acc = 0.f;
    if (which == 0) {
      #pragma unroll 8
      for (int d = 0; d < DD; ++d) acc += A[d*5+e] * Bsh[d*5+f];
      acc *= 0.125f * 1.44269504088896340736f;   // fold log2(e) for exp2
    } else {
      #pragma unroll 8
      for (int d = 0; d < DD; ++d) acc += A[d*5+e] * Bsh[f*64+d];
    }
    mp[which*960 + ((l*NH + h)*EDIM + e)*8 + f] = acc;
  }
}

// ---------------------------------------------------------------------------
// Kernel 2: one workgroup (256 thr = 4 waves) per batch element.
//   wave == head.  Token state is REGISTER-resident, distributed across
//   lanes: lane i holds token i (slot A) and token i+64 (slot B, rare).
//   j-loop fetches o[j] via v_readlane (wave-uniform j) -> ZERO memory ops
//   in the hot loop.  Each wave owns the complete softmax row, so wp is
//   pre-normalized before the LDS exchange (no ls traffic, one rcp/row).
//   Cross-wave traffic: wp[5] per (head,row), parity double-buffered ->
//   ONE barrier per layer.  Token update (o += sum_h wp, LN/FFN/LN) runs
//   redundantly in every wave on its own lanes; deterministic FP keeps all
//   4 register copies bit-identical.
//   Rep row (index nm): a=0 so exp2(0)=1 gives uniform weights; correction
//   w += (100-nm)*o_rep; inv = 1/100.
//   __launch_bounds__(256,4): 4 waves/EU -> VGPR cap 128 (NO spill; round-2
//   used (512,8) = cap 64 -> 44 MB/dispatch scratch traffic, ERRATA #9).
// ---------------------------------------------------------------------------
__global__ __launch_bounds__(BLK, 4) void encoder_kernel(
    const float* __restrict__ x,
    const float* __restrict__ mp,
    const float* __restrict__ Wf,
    const float* __restrict__ bfv,
    const float* __restrict__ g1,
    const float* __restrict__ b1,
    const float* __restrict__ g2,
    const float* __restrict__ b2,
    float* __restrict__ out)
{
  const int b = blockIdx.x, t = threadIdx.x;
  const int wv = t >> 6, ln = t & 63;     // wave == head

  __shared__ float4 s_MP4[480];            // 7680 B : M then P
  __shared__ float4 s_wp4[2][NH][104];     // 13312 B: wp[0..3], parity dbuf
  __shared__ float  s_wp1[2][NH][104];     // 3328 B : wp[4]
  __shared__ float4 s_i4[104];             // 1664 B : staging / final state
  __shared__ float  s_i1[104];             // 416 B
  __shared__ int    s_cidx[NTOK];          // 400 B
  __shared__ unsigned long long s_bal[2];

  const float* mpf = (const float*)s_MP4;
  for (int r = t; r < 480; r += BLK) s_MP4[r] = ((const float4*)mp)[r];
  for (int r = t; r < 104; r += BLK) { s_i4[r] = make_float4(0.f,0.f,0.f,0.f); s_i1[r] = 0.f; }

  // ---- setup: mask + ballot compaction into LDS staging ----
  float k0=0.f, k1=0.f, k2=0.f, msk=0.f;
  if (t < NTOK) {
    k0 = x[b*300 + 3*t];
    k1 = x[b*300 + 3*t + 1];
    k2 = x[b*300 + 3*t + 2];
    msk = (k2 > 0.f) ? 1.f : 0.f;
  }
  unsigned long long bal = __ballot(t < NTOK && msk != 0.f);
  if (t == 0)  s_bal[0] = bal;
  if (t == 64) s_bal[1] = bal;
  __syncthreads();
  const unsigned long long bw0 = s_bal[0], bw1 = s_bal[1];
  const int nm = __popcll(bw0) + __popcll(bw1);     // # unmasked tokens
  if (t < NTOK) {
    int lane = t & 63;
    unsigned long long lm = (lane == 0) ? 0ull : ((1ull << lane) - 1ull);
    int pre = (t < 64) ? __popcll(bw0 & lm) : (__popcll(bw0) + __popcll(bw1 & lm));
    if (msk != 0.f) {
      s_i4[pre] = make_float4(k0, k1, k2, sinf((float)t));
      s_i1[pre] = cosf((float)t);
      s_cidx[t] = pre;
    } else {
      s_cidx[t] = nm;
    }
  }
  __syncthreads();

  const int rows = nm + 1;                  // includes rep token at index nm
  const bool twoRows = (rows > 64);

  // ---- register-resident token state (identical in every wave) ----
  float oA0,oA1,oA2,oA3,oA4, oB0,oB1,oB2,oB3,oB4;
  { float4 v = s_i4[ln]; oA0=v.x; oA1=v.y; oA2=v.z; oA3=v.w; oA4=s_i1[ln]; }
  { float4 v = s_i4[ln+40]; oB0=v.x; oB1=v.y; oB2=v.z; oB3=v.w; oB4=s_i1[ln+40]; }
  if (ln >= 40) { oB0=0.f; oB1=0.f; oB2=0.f; oB3=0.f; oB4=0.f; }
  else if (!twoRows) { oB0=0.f; oB1=0.f; oB2=0.f; oB3=0.f; oB4=0.f; }
  // (slot B holds token ln+64; loaded via ln+40? no -- see below, reload)
  if (twoRows && ln < 40) {
    float4 v = s_i4[ln+64]; oB0=v.x; oB1=v.y; oB2=v.z; oB3=v.w; oB4=s_i1[ln+64];
  } else { oB0=0.f; oB1=0.f; oB2=0.f; oB3=0.f; oB4=0.f; }

  const int jhiA = (nm < 64) ? nm : 64;     // slot-A keys (j < 64)
  const float wext = (float)(NTOK - nm);
  int bufp = 0;

  for (int l = 0; l < NL; ++l) {
    const float* Mh = mpf + ((l*NH + wv)*EDIM)*8;
    const float* Ph = mpf + 960 + ((l*NH + wv)*EDIM)*8;

    // ---- attention + P-apply for one register-held row ----
    auto attn_row = [&](float o0,float o1,float o2,float o3,float o4,int row) {
      float oc[5] = {o0,o1,o2,o3,o4};
      float a0=0.f,a1=0.f,a2=0.f,a3=0.f,a4=0.f;
      #pragma unroll
      for (int e = 0; e < 5; ++e) {
        float4 mr = *(const float4*)(Mh + e*8); float m4 = Mh[e*8+4];
        a0 += oc[e]*mr.x; a1 += oc[e]*mr.y; a2 += oc[e]*mr.z;
        a3 += oc[e]*mr.w; a4 += oc[e]*m4;
      }
      const bool rep = (row == nm);
      if (rep) { a0=0.f; a1=0.f; a2=0.f; a3=0.f; a4=0.f; }   // exp2(0)=1
      float ls=0.f, w0=0.f, w1=0.f, w2=0.f, w3=0.f, w4=0.f;
      #pragma unroll 4
      for (int j = 0; j < jhiA; ++j) {        // keys in slot A (j<64)
        float ox = RL(oA0,j), oy = RL(oA1,j), oz = RL(oA2,j),
              ow = RL(oA3,j), oe = RL(oA4,j);
        float s = a0*ox + a1*oy + a2*oz + a3*ow + a4*oe;
        float p = EXP2(s);
        ls += p;
        w0 += p*ox; w1 += p*oy; w2 += p*oz; w3 += p*ow; w4 += p*oe;
      }
      if (twoRows) {
        #pragma unroll 4
        for (int j = 64; j < nm; ++j) {       // keys in slot B (j>=64)
          int jl = j - 64;
          float ox = RL(oB0,jl), oy = RL(oB1,jl), oz = RL(oB2,jl),
                ow = RL(oB3,jl), oe = RL(oB4,jl);
          float s = a0*ox + a1*oy + a2*oz + a3*ow + a4*oe;
          float p = EXP2(s);
          ls += p;
          w0 += p*ox; w1 += p*oy; w2 += p*oz; w3 += p*ow; w4 += p*oe;
        }
      }
      if (rep) {   // masked keys all carry the rep state
        w0 += wext*o0; w1 += wext*o1; w2 += wext*o2; w3 += wext*o3; w4 += wext*o4;
      }
      float inv = rep ? 0.01f : RCPF(ls);     // pre-normalize (full row here)
      float wc[5] = {w0*inv, w1*inv, w2*inv, w3*inv, w4*inv};
      float c0=0.f,c1=0.f,c2=0.f,c3=0.f,c4=0.f;   // wp = (w/ls) @ P
      #pragma unroll
      for (int e = 0; e < 5; ++e) {
        float4 pr = *(const float4*)(Ph + e*8); float p4 = Ph[e*8+4];
        c0 += wc[e]*pr.x; c1 += wc[e]*pr.y; c2 += wc[e]*pr.z;
        c3 += wc[e]*pr.w; c4 += wc[e]*p4;
      }
      if (row < rows) {
        s_wp4[bufp][wv][row] = make_float4(c0,c1,c2,c3);
        s_wp1[bufp][wv][row] = c4;
      }
    };

    attn_row(oA0,oA1,oA2,oA3,oA4, ln);
    if (twoRows) attn_row(oB0,oB1,oB2,oB3,oB4, ln+64);
    __syncthreads();   // the ONLY barrier per layer (wp parity dbuf)

    // ---- token update: redundant in every wave (regs stay coherent) ----
    auto upd = [&](float& p0,float& p1,float& p2,float& p3,float& p4,int row) {
      if (row >= rows) return;
      float y0=p0, y1=p1, y2=p2, y3=p3, y4=p4;
      #pragma unroll
      for (int hh = 0; hh < NH; ++hh) {
        float4 wA = s_wp4[bufp][hh][row];
        y0 += wA.x; y1 += wA.y; y2 += wA.z; y3 += wA.w;
        y4 += s_wp1[bufp][hh][row];
      }
      float yv[5] = {y0,y1,y2,y3,y4};
      float mu = 0.2f*(y0+y1+y2+y3+y4);
      float var = 0.f;
      #pragma unroll
      for (int e = 0; e < 5; ++e) { float d = yv[e]-mu; var += d*d; }
      var *= 0.2f;
      float iv = 1.f / sqrtf(var + 1e-5f);
      float l1[5];
      #pragma unroll
      for (int e = 0; e < 5; ++e) l1[e] = (yv[e]-mu)*iv*g1[l*5+e] + b1[l*5+e];
      float r2[5];
      #pragma unroll
      for (int e = 0; e < 5; ++e) {
        float acc = bfv[l*5+e];
        #pragma unroll
        for (int f = 0; f < 5; ++f) acc += l1[f]*Wf[(l*5+e)*5+f];
        acc = acc > 0.f ? acc : 0.f;
        r2[e] = acc + l1[e];
      }
      float mu2 = 0.2f*(r2[0]+r2[1]+r2[2]+r2[3]+r2[4]);
      float var2 = 0.f;
      #pragma unroll
      for (int e = 0; e < 5; ++e) { float d = r2[e]-mu2; var2 += d*d; }
      var2 *= 0.2f;
      float iv2 = 1.f / sqrtf(var2 + 1e-5f);
      p0 = (r2[0]-mu2)*iv2*g2[l*5+0] + b2[l*5+0];
      p1 = (r2[1]-mu2)*iv2*g2[l*5+1] + b2[l*5+1];
      p2 = (r2[2]-mu2)*iv2*g2[l*5+2] + b2[l*5+2];
      p3 = (r2[3]-mu2)*iv2*g2[l*5+3] + b2[l*5+3];
      p4 = (r2[4]-mu2)*iv2*g2[l*5+4] + b2[l*5+4];
    };
    upd(oA0,oA1,oA2,oA3,oA4, ln);
    if (twoRows) upd(oB0,oB1,oB2,oB3,oB4, ln+64);
    bufp ^= 1;
    // no trailing barrier: next layer writes the OTHER wp buffer, and the
    // layer-(l+1) barrier separates this layer's reads from layer-(l+2)'s
    // writes to this buffer.
  }

  // ---- writeback: wave 0's registers -> LDS, then expand to [N,E] ----
  __syncthreads();   // all waves done reading wp/s_i4 from setup
  if (wv == 0) {
    if (ln < rows) { s_i4[ln] = make_float4(oA0,oA1,oA2,oA3); s_i1[ln] = oA4; }
    if (twoRows && (ln + 64 < rows)) {
      s_i4[ln+64] = make_float4(oB0,oB1,oB2,oB3); s_i1[ln+64] = oB4;
    }
  }
  __syncthreads();
  for (int r = t; r < NTOK*EDIM; r += BLK) {
    int i = r / EDIM;
    int e = r - i*EDIM;
    int c = s_cidx[i];
    float v = (e < 4) ? ((const float*)&s_i4[c])[e] : s_i1[c];
    out[b*(NTOK*EDIM) + r] = v;
  }
}

extern "C" void kernel_launch(void* const* d_in, const int* in_sizes, int n_in,
                              void* d_out, int out_size, void* d_ws, size_t ws_size,
                              hipStream_t stream) {
  const float* x  = (const float*)d_in[0];
  const float* Wq = (const float*)d_in[1];
  const float* Wk = (const float*)d_in[2];
  const float* Wv = (const float*)d_in[3];
  const float* Wo = (const float*)d_in[4];
  const float* Wf = (const float*)d_in[5];
  const float* bf = (const float*)d_in[6];
  const float* g1 = (const float*)d_in[7];
  const float* b1 = (const float*)d_in[8];
  const float* g2 = (const float*)d_in[9];
  const float* b2 = (const float*)d_in[10];
  float* outp = (float*)d_out;
  float* mp   = (float*)d_ws;   // 1920 floats

  precompute_mp<<<24, 64, 0, stream>>>(Wq, Wk, Wv, Wo, mp);
  encoder_kernel<<<1024, BLK, 0, stream>>>(x, mp, Wf, bf, g1, b1, g2, b2, outp);
}

// Round 4
// 128.787 us; speedup vs baseline: 1.1381x; 1.0091x over previous
//
#include <hip/hip_runtime.h>
#include <math.h>

#define NTOK 100
#define EDIM 5
#define NH   4
#define NL   3
#define DD   64
#define BLK  256

// single-instruction transcendentals (1-ulp class; tolerance is 2^-7)
__device__ __forceinline__ float fexp2(float x){ float r; asm("v_exp_f32 %0, %1" : "=v"(r) : "v"(x)); return r; }
__device__ __forceinline__ float frcp (float x){ float r; asm("v_rcp_f32 %0, %1" : "=v"(r) : "v"(x)); return r; }
__device__ __forceinline__ float frsq (float x){ float r; asm("v_rsq_f32 %0, %1" : "=v"(r) : "v"(x)); return r; }
// wave-uniform register broadcast: v_readlane_b32 (lane index MUST be
// compiler-provably uniform -> see readfirstlane(nm) below)
#define RL(v, l) __int_as_float(__builtin_amdgcn_readlane(__float_as_int(v), (l)))

// ---------------------------------------------------------------------------
// Kernel 1: fold per-head projections into 5x5 matrices.
//   M[l][h] = (1/8)*log2(e) * Wq^T Wk    (softmax uses native v_exp_f32)
//   P[l][h] = Wv^T Wo_h^T
// ws layout: float [2][NL][NH][EDIM][8]
// ---------------------------------------------------------------------------
__global__ void precompute_mp(const float* __restrict__ Wq,
                              const float* __restrict__ Wk,
                              const float* __restrict__ Wv,
                              const float* __restrict__ Wo,
                              float* __restrict__ mp) {
  const int blk = blockIdx.x;            // 24 = which(2) * l(3) * h(4)
  const int which = blk / 12;
  const int rem = blk % 12;
  const int l = rem / 4, h = rem % 4;
  const int t = threadIdx.x;             // 64 threads

  __shared__ float A[320];               // [d*5+e]
  __shared__ float Bsh[320];             // which0: [d*5+f] ; which1: [f*64+d]

  const float* wa = (which ? Wv : Wq) + (l*NH + h)*DD*EDIM;
  for (int r = t; r < 320; r += 64) A[r] = wa[r];
  if (which == 0) {
    const float* wk = Wk + (l*NH + h)*DD*EDIM;
    for (int r = t; r < 320; r += 64) Bsh[r] = wk[r];
  } else {
    for (int r = t; r < 320; r += 64) {
      int f = r >> 6, d = r & 63;
      Bsh[r] = Wo[(l*EDIM + f)*(NH*DD) + h*DD + d];
    }
  }
  __syncthreads();
  if (t < 25) {
    int e = t / 5, f = t % 5;
    float acc = 0.f;
    if (which == 0) {
      #pragma unroll 8
      for (int d = 0; d < DD; ++d) acc += A[d*5+e] * Bsh[d*5+f];
      acc *= 0.125f * 1.44269504088896340736f;   // fold log2(e) for exp2
    } else {
      #pragma unroll 8
      for (int d = 0; d < DD; ++d) acc += A[d*5+e] * Bsh[f*64+d];
    }
    mp[which*960 + ((l*NH + h)*EDIM + e)*8 + f] = acc;
  }
}

// ---------------------------------------------------------------------------
// Kernel 2: one workgroup (256 thr = 4 waves) per batch element.
//   wave == head.  Token state REGISTER-resident: lane i holds token i
//   (slot A) / token i+64 (slot B, rare).  j-loop fetches o[j] with
//   v_readlane from the wave's OWN registers -> zero memory ops, no
//   cross-wave hazard on o.  nm is readfirstlane'd so the loop bounds and
//   lane indices are PROVABLY uniform (otherwise LLVM treats the
//   LDS-derived nm as divergent and scalarizes every readlane -- the
//   round-3 2.2x instruction bloat).
//   Each wave owns the full softmax row -> wp pre-normalized; cross-wave
//   traffic is wp[5] per (head,row), parity double-buffered -> ONE barrier
//   per layer.  Token update runs redundantly in every wave (same
//   wall-time as split: issue is per-wave) keeping register copies
//   bit-identical.
//   Rep row (index nm): a=0 so exp2(0)=1 -> uniform weights; correction
//   w += (100-nm)*o_rep; inv = 1/100.
// ---------------------------------------------------------------------------
__global__ __launch_bounds__(BLK, 4) void encoder_kernel(
    const float* __restrict__ x,
    const float* __restrict__ mp,
    const float* __restrict__ Wf,
    const float* __restrict__ bfv,
    const float* __restrict__ g1,
    const float* __restrict__ b1,
    const float* __restrict__ g2,
    const float* __restrict__ b2,
    float* __restrict__ out)
{
  const int b = blockIdx.x, t = threadIdx.x;
  const int wv = t >> 6, ln = t & 63;     // wave == head

  __shared__ float4 s_MP4[480];            // 7680 B : M then P
  __shared__ float4 s_wp4[2][NH][104];     // 13312 B: wp[0..3], parity dbuf
  __shared__ float  s_wp1[2][NH][104];     // 3328 B : wp[4]
  __shared__ float4 s_i4[104];             // 1664 B : staging / final state
  __shared__ float  s_i1[104];             // 416 B
  __shared__ int    s_cidx[NTOK];          // 400 B
  __shared__ unsigned long long s_bal[2];

  const float* mpf = (const float*)s_MP4;
  for (int r = t; r < 480; r += BLK) s_MP4[r] = ((const float4*)mp)[r];
  for (int r = t; r < 104; r += BLK) { s_i4[r] = make_float4(0.f,0.f,0.f,0.f); s_i1[r] = 0.f; }

  // ---- setup: mask + ballot compaction into LDS staging ----
  float k0=0.f, k1=0.f, k2=0.f, msk=0.f;
  if (t < NTOK) {
    k0 = x[b*300 + 3*t];
    k1 = x[b*300 + 3*t + 1];
    k2 = x[b*300 + 3*t + 2];
    msk = (k2 > 0.f) ? 1.f : 0.f;
  }
  unsigned long long bal = __ballot(t < NTOK && msk != 0.f);
  if (t == 0)  s_bal[0] = bal;
  if (t == 64) s_bal[1] = bal;
  __syncthreads();
  const unsigned long long bw0 = s_bal[0], bw1 = s_bal[1];
  // readfirstlane: make nm (and everything derived) PROVABLY uniform
  const int nm = __builtin_amdgcn_readfirstlane(__popcll(bw0) + __popcll(bw1));
  if (t < NTOK) {
    int lane = t & 63;
    unsigned long long lm = (lane == 0) ? 0ull : ((1ull << lane) - 1ull);
    int pre = (t < 64) ? __popcll(bw0 & lm) : (__popcll(bw0) + __popcll(bw1 & lm));
    if (msk != 0.f) {
      s_i4[pre] = make_float4(k0, k1, k2, __sinf((float)t));
      s_i1[pre] = __cosf((float)t);
      s_cidx[t] = pre;
    } else {
      s_cidx[t] = nm;
    }
  }
  __syncthreads();

  const int rows = nm + 1;                  // includes rep token at index nm
  const bool twoRows = (rows > 64);
  const int jhiA = (nm < 64) ? nm : 64;     // slot-A keys (j < 64)
  const float wext = (float)(NTOK - nm);

  // ---- register-resident token state (identical in every wave) ----
  float oA0,oA1,oA2,oA3,oA4, oB0,oB1,oB2,oB3,oB4;
  { float4 v = s_i4[ln]; oA0=v.x; oA1=v.y; oA2=v.z; oA3=v.w; oA4=s_i1[ln]; }
  if (twoRows && ln < 40) {
    float4 v = s_i4[ln+64]; oB0=v.x; oB1=v.y; oB2=v.z; oB3=v.w; oB4=s_i1[ln+64];
  } else { oB0=0.f; oB1=0.f; oB2=0.f; oB3=0.f; oB4=0.f; }

  int bufp = 0;

  for (int l = 0; l < NL; ++l) {
    const float* Mh = mpf + ((l*NH + wv)*EDIM)*8;
    const float* Ph = mpf + 960 + ((l*NH + wv)*EDIM)*8;

    // ---- attention + P-apply for one register-held row ----
    auto attn_row = [&](float o0,float o1,float o2,float o3,float o4,int row) {
      float oc[5] = {o0,o1,o2,o3,o4};
      float a0=0.f,a1=0.f,a2=0.f,a3=0.f,a4=0.f;
      #pragma unroll
      for (int e = 0; e < 5; ++e) {
        float4 mr = *(const float4*)(Mh + e*8); float m4 = Mh[e*8+4];
        a0 += oc[e]*mr.x; a1 += oc[e]*mr.y; a2 += oc[e]*mr.z;
        a3 += oc[e]*mr.w; a4 += oc[e]*m4;
      }
      const bool rep = (row == nm);
      if (rep) { a0=0.f; a1=0.f; a2=0.f; a3=0.f; a4=0.f; }   // exp2(0)=1
      float ls=0.f, w0=0.f, w1=0.f, w2=0.f, w3=0.f, w4=0.f;
      #pragma unroll 4
      for (int j = 0; j < jhiA; ++j) {        // keys in slot A (j<64)
        float ox = RL(oA0,j), oy = RL(oA1,j), oz = RL(oA2,j),
              ow = RL(oA3,j), oe = RL(oA4,j);
        float s = (a0*ox + a1*oy) + ((a2*oz + a3*ow) + a4*oe);  // depth-3 tree
        float p = fexp2(s);
        ls += p;
        w0 += p*ox; w1 += p*oy; w2 += p*oz; w3 += p*ow; w4 += p*oe;
      }
      if (twoRows) {
        #pragma unroll 4
        for (int j = 64; j < nm; ++j) {       // keys in slot B (j>=64)
          int jl = j - 64;
          float ox = RL(oB0,jl), oy = RL(oB1,jl), oz = RL(oB2,jl),
                ow = RL(oB3,jl), oe = RL(oB4,jl);
          float s = (a0*ox + a1*oy) + ((a2*oz + a3*ow) + a4*oe);
          float p = fexp2(s);
          ls += p;
          w0 += p*ox; w1 += p*oy; w2 += p*oz; w3 += p*ow; w4 += p*oe;
        }
      }
      if (rep) {   // masked keys all carry the rep state
        w0 += wext*o0; w1 += wext*o1; w2 += wext*o2; w3 += wext*o3; w4 += wext*o4;
      }
      float inv = rep ? 0.01f : frcp(ls);     // pre-normalize (full row here)
      float wc[5] = {w0*inv, w1*inv, w2*inv, w3*inv, w4*inv};
      float c0=0.f,c1=0.f,c2=0.f,c3=0.f,c4=0.f;   // wp = (w/ls) @ P
      #pragma unroll
      for (int e = 0; e < 5; ++e) {
        float4 pr = *(const float4*)(Ph + e*8); float p4 = Ph[e*8+4];
        c0 += wc[e]*pr.x; c1 += wc[e]*pr.y; c2 += wc[e]*pr.z;
        c3 += wc[e]*pr.w; c4 += wc[e]*p4;
      }
      if (row < rows) {
        s_wp4[bufp][wv][row] = make_float4(c0,c1,c2,c3);
        s_wp1[bufp][wv][row] = c4;
      }
    };

    attn_row(oA0,oA1,oA2,oA3,oA4, ln);
    if (twoRows) attn_row(oB0,oB1,oB2,oB3,oB4, ln+64);
    __syncthreads();   // the ONLY barrier per layer (wp parity dbuf)

    // ---- token update: redundant in every wave (regs stay coherent) ----
    auto upd = [&](float& p0,float& p1,float& p2,float& p3,float& p4,int row) {
      if (row >= rows) return;
      float y0=p0, y1=p1, y2=p2, y3=p3, y4=p4;
      #pragma unroll
      for (int hh = 0; hh < NH; ++hh) {
        float4 wA = s_wp4[bufp][hh][row];
        y0 += wA.x; y1 += wA.y; y2 += wA.z; y3 += wA.w;
        y4 += s_wp1[bufp][hh][row];
      }
      float yv[5] = {y0,y1,y2,y3,y4};
      float mu = 0.2f*(y0+y1+y2+y3+y4);
      float var = 0.f;
      #pragma unroll
      for (int e = 0; e < 5; ++e) { float d = yv[e]-mu; var += d*d; }
      float iv = frsq(var*0.2f + 1e-5f);
      float l1[5];
      #pragma unroll
      for (int e = 0; e < 5; ++e) l1[e] = (yv[e]-mu)*iv*g1[l*5+e] + b1[l*5+e];
      float r2[5];
      #pragma unroll
      for (int e = 0; e < 5; ++e) {
        float acc = bfv[l*5+e];
        #pragma unroll
        for (int f = 0; f < 5; ++f) acc += l1[f]*Wf[(l*5+e)*5+f];
        acc = acc > 0.f ? acc : 0.f;
        r2[e] = acc + l1[e];
      }
      float mu2 = 0.2f*(r2[0]+r2[1]+r2[2]+r2[3]+r2[4]);
      float var2 = 0.f;
      #pragma unroll
      for (int e = 0; e < 5; ++e) { float d = r2[e]-mu2; var2 += d*d; }
      float iv2 = frsq(var2*0.2f + 1e-5f);
      p0 = (r2[0]-mu2)*iv2*g2[l*5+0] + b2[l*5+0];
      p1 = (r2[1]-mu2)*iv2*g2[l*5+1] + b2[l*5+1];
      p2 = (r2[2]-mu2)*iv2*g2[l*5+2] + b2[l*5+2];
      p3 = (r2[3]-mu2)*iv2*g2[l*5+3] + b2[l*5+3];
      p4 = (r2[4]-mu2)*iv2*g2[l*5+4] + b2[l*5+4];
    };
    upd(oA0,oA1,oA2,oA3,oA4, ln);
    if (twoRows) upd(oB0,oB1,oB2,oB3,oB4, ln+64);
    bufp ^= 1;
    // no trailing barrier: next layer writes the OTHER wp buffer; the
    // per-layer barrier separates this layer's reads from the next write
    // to the same parity.
  }

  // ---- writeback: wave 0's registers -> LDS, then expand to [N,E] ----
  if (wv == 0) {
    if (ln < rows) { s_i4[ln] = make_float4(oA0,oA1,oA2,oA3); s_i1[ln] = oA4; }
    if (twoRows && (ln + 64 < rows)) {
      s_i4[ln+64] = make_float4(oB0,oB1,oB2,oB3); s_i1[ln+64] = oB4;
    }
  }
  __syncthreads();
  for (int r = t; r < NTOK*EDIM; r += BLK) {
    int i = r / EDIM;
    int e = r - i*EDIM;
    int c = s_cidx[i];
    float v = (e < 4) ? ((const float*)&s_i4[c])[e] : s_i1[c];
    out[b*(NTOK*EDIM) + r] = v;
  }
}

extern "C" void kernel_launch(void* const* d_in, const int* in_sizes, int n_in,
                              void* d_out, int out_size, void* d_ws, size_t ws_size,
                              hipStream_t stream) {
  const float* x  = (const float*)d_in[0];
  const float* Wq = (const float*)d_in[1];
  const float* Wk = (const float*)d_in[2];
  const float* Wv = (const float*)d_in[3];
  const float* Wo = (const float*)d_in[4];
  const float* Wf = (const float*)d_in[5];
  const float* bf = (const float*)d_in[6];
  const float* g1 = (const float*)d_in[7];
  const float* b1 = (const float*)d_in[8];
  const float* g2 = (const float*)d_in[9];
  const float* b2 = (const float*)d_in[10];
  float* outp = (float*)d_out;
  float* mp   = (float*)d_ws;   // 1920 floats

  precompute_mp<<<24, 64, 0, stream>>>(Wq, Wk, Wv, Wo, mp);
  encoder_kernel<<<1024, BLK, 0, stream>>>(x, mp, Wf, bf, g1, b1, g2, b2, outp);
}